// Round 10
// baseline (265.442 us; speedup 1.0000x reference)
//
#include <hip/hip_runtime.h>

#define MDIM 8192
#define NDIM 8192
#define KDIM 64

typedef __attribute__((ext_vector_type(8))) short bf16x8;
typedef __attribute__((ext_vector_type(4))) float f32x4;

__device__ __forceinline__ unsigned short f32_to_bf16(float f) {
    union { float f; unsigned int u; } v;
    v.f = f;
    unsigned int u = v.u;
    u += 0x7FFFu + ((u >> 16) & 1u);  // round-to-nearest-even
    return (unsigned short)(u >> 16);
}

// ---------------------------------------------------------------------------
// R10: 256x512 tile (vs 128x128). Theory: writes were never the whole story --
// per-block READS equal writes (64 KB vs 64 KB at 128x128), and C's
// write-allocate stream thrashes L2 (32+ MB C per 4 MB XCD-L2) and LLC
// (268 MB through 256 MB), so A/B panel re-reads go back to HBM:
// HBM ~ 268 wr + ~250 rd = 520 MB -> 82 us, matching the observed ~92 us
// that six write-side experiments (R1..R9) could not move.
// Tile area sets the re-read factor: 256x512 cuts cumulative reads
// 256 MB -> 96 MB  =>  predicted ~57-65 us kernel.
//
// Structure: 512 threads (8 waves), 128 KB LDS:
//   sA  [0,32K):   256 m x 64 k bf16, XOR-swizzled (R2 layout)
//   sB  [32K,96K): 512 n x 64 k bf16, XOR-swizzled
//   bounce [96K,128K): 8 waves x 4 KB private slabs (R8 single-slab epilogue)
// One barrier total (after staging). Per m-slice (64 rows), each wave owns a
// 64x64 sub-tile = byte-identical R6 fragment/MFMA/epilogue code. Plain
// stores (R6 winner). 1 block/CU, grid 512 = 2 generations.
// ---------------------------------------------------------------------------
__global__ __launch_bounds__(512, 1)
void tmatmul_kernel(const float* __restrict__ A, const float* __restrict__ B,
                    float* __restrict__ C) {
    __shared__ __align__(16) unsigned short smem[65536];  // 128 KB
    unsigned short* sA = smem;           // 32 KB
    unsigned short* sB = smem + 16384;   // 64 KB

    const int tid = threadIdx.x;
    const int m0 = blockIdx.y << 8;  // 256-row band
    const int n0 = blockIdx.x << 9;  // 512-col band

    // ---- Stage A: 256x64 fp32 = 64 KB, fully linear float4 reads. ----
#pragma unroll
    for (int i = 0; i < 8; ++i) {
        const int f = (i << 11) + (tid << 2);  // linear float idx in A slab
        const int row = f >> 6;
        const int col = f & 63;
        const float4 v = *reinterpret_cast<const float4*>(&A[(size_t)m0 * KDIM + f]);
        ushort4 h;
        h.x = f32_to_bf16(v.x);
        h.y = f32_to_bf16(v.y);
        h.z = f32_to_bf16(v.z);
        h.w = f32_to_bf16(v.w);
        *reinterpret_cast<ushort4*>(
            &sA[row * 64 + (((col >> 3) ^ (row & 7)) << 3) + (col & 7)]) = h;
    }

    // ---- Stage B: 64x512 fp32 transposed into sB[n][k] (R6 pattern). ----
    // (n, k0-group) bijection over 512 threads x 16 iters:
    //   n  = (tid&63) + (i&7)*64        in [0,512)
    //   k0 = (tid>>6)*4 + (i>>3)*32     in {0,4,...,60}
#pragma unroll
    for (int i = 0; i < 16; ++i) {
        const int n = (tid & 63) + ((i & 7) << 6);
        const int k0 = ((tid >> 6) << 2) + ((i >> 3) << 5);
        const size_t gb = (size_t)k0 * NDIM + n0 + n;
        ushort4 h;
        h.x = f32_to_bf16(B[gb]);
        h.y = f32_to_bf16(B[gb + NDIM]);
        h.z = f32_to_bf16(B[gb + 2 * NDIM]);
        h.w = f32_to_bf16(B[gb + 3 * NDIM]);
        *reinterpret_cast<ushort4*>(
            &sB[n * 64 + (((k0 >> 3) ^ (n & 7)) << 3) + (k0 & 7)]) = h;
    }

    __syncthreads();  // the ONLY barrier: sA/sB never overwritten afterwards

    const int lane = tid & 63;
    const int wv = tid >> 6;        // 0..7
    const int wn = wv << 6;         // wave's n base within tile (64-wide)
    const int l15 = lane & 15;
    const int quad = lane >> 4;
    const int x = l15 & 7;          // row-dependent XOR key
    const char* sAb = (const char*)sA;
    const char* sBb = (const char*)sB;
    float* buf = reinterpret_cast<float*>((char*)smem + 98304 + (wv << 12));

    const f32x4 zero = {0.0f, 0.0f, 0.0f, 0.0f};

    // ---- 4 m-slices of 64 rows; per slice each wave = proven R6 64x64. ----
#pragma unroll
    for (int ms = 0; ms < 4; ++ms) {
        bf16x8 afrag[4][2];
#pragma unroll
        for (int mt = 0; mt < 4; ++mt)
#pragma unroll
            for (int ks = 0; ks < 2; ++ks)
                afrag[mt][ks] = *reinterpret_cast<const bf16x8*>(
                    sAb + ((ms << 6) + (mt << 4) + l15) * 128 +
                    (((ks * 4 + quad) ^ x) << 4));

        f32x4 acc[4][4];
#pragma unroll
        for (int mt = 0; mt < 4; ++mt)
#pragma unroll
            for (int nt = 0; nt < 4; ++nt)
                acc[mt][nt] = zero;

        // Operand swap (proven): lane holds C[m=l15][n=quad*4+reg] per tile.
#pragma unroll
        for (int nt = 0; nt < 4; ++nt) {
            const char* rb = sBb + (wn + nt * 16 + l15) * 128;
            const bf16x8 bf0 =
                *reinterpret_cast<const bf16x8*>(rb + ((quad ^ x) << 4));
            const bf16x8 bf1 =
                *reinterpret_cast<const bf16x8*>(rb + (((4 + quad) ^ x) << 4));
#pragma unroll
            for (int mt = 0; mt < 4; ++mt) {
                acc[mt][nt] = __builtin_amdgcn_mfma_f32_16x16x32_bf16(
                    bf0, afrag[mt][0], acc[mt][nt], 0, 0, 0);
                acc[mt][nt] = __builtin_amdgcn_mfma_f32_16x16x32_bf16(
                    bf1, afrag[mt][1], acc[mt][nt], 0, 0, 0);
            }
        }

        // ---- Epilogue (R6 bounce, R8 single-slab; slab is wave-private so
        //      no barrier needed). 4 rows x 256 B per plain store instr. ----
#pragma unroll
        for (int mt = 0; mt < 4; ++mt) {
#pragma unroll
            for (int nt = 0; nt < 4; ++nt) {
                const int g = (nt << 2) + quad;
                *reinterpret_cast<f32x4*>(&buf[(l15 << 6) + ((g ^ l15) << 2)]) =
                    acc[mt][nt];
            }
            const int m_base = m0 + (ms << 6) + (mt << 4);
            const int n_base = n0 + wn + (l15 << 2);
#pragma unroll
            for (int j = 0; j < 4; ++j) {
                const int rr = (j << 2) + quad;
                const f32x4 v = *reinterpret_cast<const f32x4*>(
                    &buf[(rr << 6) + ((l15 ^ rr) << 2)]);
                *reinterpret_cast<f32x4*>(
                    &C[(size_t)(m_base + rr) * NDIM + n_base]) = v;
            }
        }
    }
}

extern "C" void kernel_launch(void* const* d_in, const int* in_sizes, int n_in,
                              void* d_out, int out_size, void* d_ws, size_t ws_size,
                              hipStream_t stream) {
    const float* A = (const float*)d_in[0];
    const float* B = (const float*)d_in[1];
    float* C = (float*)d_out;
    dim3 grid(NDIM / 512, MDIM / 256);  // (16, 32) = 512 blocks
    tmatmul_kernel<<<grid, dim3(512, 1, 1), 0, stream>>>(A, B, C);
}